// Round 11
// baseline (2789.425 us; speedup 1.0000x reference)
//
#include <hip/hip_runtime.h>

typedef unsigned int u32;
typedef unsigned short u16;
typedef unsigned long long u64;
typedef __attribute__((ext_vector_type(8))) short short8;
typedef __attribute__((ext_vector_type(4))) float f32x4;
typedef __attribute__((ext_vector_type(4))) u32 u32x4;

#define SEQ 512
#define BATCH 32
#define DIM 1024
#define NB 128   // persistent blocks in recurrent kernel

// workspace layout (bytes)
#define OFF_XT    0ull                  // bf16 [16384][1024] Xt (dead after k_gemm)
                                        // -> REUSED: h slots s=0..511, 64KB each (32MB)
#define OFF_UBT   33554432ull           // bf16 [4096][1024] U^T (dead after k_gemm)
                                        // -> REUSED: h slot "-1" = zeros (64KB)
#define OFF_WG2   41943040ull           // bf16 [128 blk][64 grp][64 lane][8] frag-order W
#define OFF_XPROJ 50331648ull           // bf16 xp2 [512 s][128 blk][4 g][8 d'][32 b]
#define OFF_BIAS  184680448ull          // f32  [4096]
#define OFF_SYNC  184696832ull          // u32 flags[512 wave][4] (16B-padded)

__device__ __forceinline__ float bf2f(u16 u) {
  union { u32 u; float f; } v; v.u = ((u32)u) << 16; return v.f;
}
__device__ __forceinline__ u16 f2bf(float f) {
  union { float f; u32 u; } v; v.f = f;
  u32 r = v.u + 0x7FFFu + ((v.u >> 16) & 1u);
  return (u16)(r >> 16);
}
// tanh(x) = 1 - 2/(1+e^{2x}) : exact identity, __expf-based
__device__ __forceinline__ float tanh_fast(float x) {
  return 1.f - 2.f / (1.f + __expf(2.f * x));
}
__device__ __forceinline__ void gload_lds16(const u16* g, u16* l) {
  __builtin_amdgcn_global_load_lds(
      (const __attribute__((address_space(1))) u32*)g,
      (__attribute__((address_space(3))) u32*)l, 16, 0, 0);
}

// ---------------- init: concat bias + zero flags --------------------------
__global__ void k_init(float* biasc, u32* sync, const float* bi,
                       const float* bfv, const float* bo, const float* bg) {
  int i = blockIdx.x * 256 + threadIdx.x;
  if (i < 4096) {
    int g = i >> 10, c = i & 1023;
    const float* p = (g == 0) ? bi : (g == 1) ? bfv : (g == 2) ? bo : bg;
    biasc[i] = p[c];
  } else if (i < 4096 + 2048) {
    sync[i - 4096] = 0u;               // 512 flags x 16B pad
  }
}

// ---------------- zero h slot -1 (UBT region; runs AFTER k_gemm) ----------
__global__ void k_zero(u32x4* p) {     // 16 blocks x 256 x 16B = 64KB
  p[blockIdx.x * 256 + threadIdx.x] = (u32x4){0u, 0u, 0u, 0u};
}

// ---------------- transpose-cast the 8 weight matrices --------------------
// (R10/R12-verified layouts, unchanged)
__global__ void k_prep_w(const float* Ui, const float* Wi, const float* Uf,
                         const float* Wf, const float* Uo, const float* Wo,
                         const float* Ug, const float* Wg, u16* Ubt, u16* Wg2) {
  __shared__ float tile[64][65];
  int bx = blockIdx.x;
  int mi = bx >> 8;
  int tt = bx & 255;
  int tr = tt >> 4, tc = tt & 15;
  const float* src;
  switch (mi) {
    case 0: src = Ui; break; case 1: src = Wi; break;
    case 2: src = Uf; break; case 3: src = Wf; break;
    case 4: src = Uo; break; case 5: src = Wo; break;
    case 6: src = Ug; break; default: src = Wg; break;
  }
  int g = mi >> 1;
  int d0 = tr * 64, c0 = tc * 64;
  int ty = threadIdx.x >> 6, tx = threadIdx.x & 63;
#pragma unroll
  for (int i = 0; i < 16; ++i) {
    int r = i * 4 + ty;
    tile[r][tx] = src[(size_t)(d0 + r) * 1024 + c0 + tx];
  }
  __syncthreads();
  if (mi & 1) {
#pragma unroll
    for (int i = 0; i < 16; ++i) {
      int cc = i * 4 + ty;
      int c_full = c0 + cc;
      int k = d0 + tx;
      int blk = c_full >> 3;
      int lane = (((k & 31) >> 3) << 4) + ((c_full & 3) << 2) + g;
      size_t idx = (size_t)blk * 32768 +
                   (size_t)(((k >> 5) * 2 + ((c_full & 7) >> 2)) * 64 + lane) * 8 +
                   (k & 7);
      Wg2[idx] = f2bf(tile[tx][cc]);
    }
  } else {
#pragma unroll
    for (int i = 0; i < 16; ++i) {
      int cc = i * 4 + ty;
      Ubt[(size_t)((g << 10) + c0 + cc) * 1024 + d0 + tx] = f2bf(tile[tx][cc]);
    }
  }
}

// ---------------- transpose-cast X: Xt[s*32+b][d] = X[b][s][d] ------------
__global__ void k_prep_x(const float* __restrict__ X, u16* __restrict__ Xt) {
  int idx = blockIdx.x * 256 + threadIdx.x;
  int m = idx >> 8, d4 = (idx & 255) << 2;
  int s = m >> 5, b = m & 31;
  const float4* p = (const float4*)(X + (size_t)(b * SEQ + s) * DIM + d4);
  float4 v = *p;
  u16 o[4] = { f2bf(v.x), f2bf(v.y), f2bf(v.z), f2bf(v.w) };
  *(ushort4*)(Xt + (size_t)m * DIM + d4) = *(ushort4*)o;
}

// ---------------- phase 1 GEMM: xp2 = Xt@U+b, LDS-coalesced epilogue ------
// (R12-verified, unchanged)  xp2: [s][blkd][g][d'][b], 2KB per (s,blkd)
__global__ __launch_bounds__(256) void k_gemm(const u16* __restrict__ Xt,
                                              const u16* __restrict__ Ubt,
                                              const float* __restrict__ biasc,
                                              u16* __restrict__ xp2) {
  __shared__ u16 As[128 * 32];
  __shared__ u16 Bs[128 * 32];
  __shared__ u16 cbuf[4][16][8][32];
  int tid = threadIdx.x;
  int w = tid >> 6, l = tid & 63;
  int n0 = blockIdx.x * 128, m0 = blockIdx.y * 128;
  int wm = w >> 1, wn = w & 1;
  int lrow = l & 15, lq = l >> 4;
  f32x4 acc[4][4] = {};
  for (int kt = 0; kt < 32; ++kt) {
    int k0 = kt * 32;
    __syncthreads();
#pragma unroll
    for (int is = 0; is < 2; ++is) {
      int c = is * 256 + w * 64 + l;
      int row = c >> 2, kg = c & 3;
      gload_lds16(Xt + (size_t)(m0 + row) * 1024 + k0 + kg * 8, As + c * 8);
      gload_lds16(Ubt + (size_t)(n0 + row) * 1024 + k0 + kg * 8, Bs + c * 8);
    }
    __syncthreads();
    short8 af[4], bfr[4];
#pragma unroll
    for (int mt = 0; mt < 4; ++mt)
      af[mt] = *(const short8*)(As + (wm * 64 + mt * 16 + lrow) * 32 + lq * 8);
#pragma unroll
    for (int nt = 0; nt < 4; ++nt)
      bfr[nt] = *(const short8*)(Bs + (wn * 64 + nt * 16 + lrow) * 32 + lq * 8);
#pragma unroll
    for (int mt = 0; mt < 4; ++mt)
#pragma unroll
      for (int nt = 0; nt < 4; ++nt)
        acc[mt][nt] = __builtin_amdgcn_mfma_f32_16x16x32_bf16(
            af[mt], bfr[nt], acc[mt][nt], 0, 0, 0);
  }
#pragma unroll
  for (int nt = 0; nt < 4; ++nt) {
    int lc = wn * 64 + nt * 16 + lrow;
    float bv = biasc[n0 + lc];
#pragma unroll
    for (int mt = 0; mt < 4; ++mt) {
#pragma unroll
      for (int r = 0; r < 4; ++r) {
        int lr = wm * 64 + mt * 16 + lq * 4 + r;
        cbuf[lr >> 5][lc >> 3][lrow & 7][lr & 31] = f2bf(acc[mt][nt][r] + bv);
      }
    }
  }
  __syncthreads();
  int s0 = m0 >> 5, blkd0 = (n0 & 1023) >> 3, gb = (n0 >> 10) * 256;
  const u16* cb = &cbuf[0][0][0][0];
#pragma unroll
  for (int i = 0; i < 8; ++i) {
    int u = i * 256 + tid;
    int r_ = u >> 5, w_ = u & 31;
    u32x4 v = *(const u32x4*)(cb + u * 8);
    *(u32x4*)(xp2 + (size_t)((s0 + (r_ >> 4)) * 128 + blkd0 + (r_ & 15)) * 1024 +
              gb + w_ * 8) = v;
  }
}

// ---------------- phase 2: persistent recurrent kernel --------------------
// R13: fully decoupled per-wave pipelines. NO barriers/syncthreads in loop.
//   Wave (blk, mt, nt): cell (d=blk*8+mt*4+q, b=nt*16+b15) per lane.
//   - per-wave flags (512, nt-major): flag = s+1 after own h-stores acked
//     (per-wave vmcnt(0)); consumer polls only the 256 same-nt flags.
//     Induction: flag_w >= s => wave w stored h(s) => its stores are
//     LLC-visible => sc-coherent loads of slot s-1..s safe. Slots are
//     per-step (no overwrite ever).
//   - h B-frags loaded DIRECTLY to registers: 32 dwordx4/wave, 3-buffer
//     4-chunk vmcnt pipeline (16/16/8/0). No Hs LDS, no DMA drain stalls.
//   - W in LDS (64KB staged once) -- R12's VGPR_Count=92 proved wf[] was
//     never register-resident; ds_read_b128 per MFMA instead, and the
//     vmcnt windows stay clean of stray W loads.
//   - xp: per-wave 1KB LDS-DMA prefetch (s+1), issued first each step,
//     drained for free by the first vmcnt(16).
__global__ __launch_bounds__(256, 1) void k_rec(const u16* __restrict__ Wg2,
                                                const u16* __restrict__ xp2,
                                                u16* hX, const u16* __restrict__ h0,
                                                u32* sync) {
  __shared__ u16 Ws[32768];          // 64KB A-frag-order W slice
  __shared__ u16 XPs[4][2][512];     // per-wave 1KB x 2 parity xp slices
  int tid = threadIdx.x;
  int w = tid >> 6, l = tid & 63;
  int mt = w >> 1, nt = w & 1;
  int blk = blockIdx.x;
  int q = l >> 4, b15 = l & 15;

  // stage Ws cooperatively (16 rounds)
#pragma unroll
  for (int it = 0; it < 16; ++it)
    gload_lds16(Wg2 + (size_t)blk * 32768 + (it * 256 + tid) * 8,
                Ws + (it * 256 + tid) * 8);
  // per-wave xp source lane offset within a (s,blk) 1024-u16 slice:
  //   g=l>>4, d'=mt*4+((l&15)>>2), b0=(l&3)*8  ->  g*256 + d'*32 + b0
  int xsrc = (l >> 4) * 256 + (mt * 4 + ((l & 15) >> 2)) * 32 + (l & 3) * 8;
  // stage XPs[w][0] for s=0
  gload_lds16(xp2 + (size_t)blk * 1024 + xsrc, &XPs[w][0][l * 8]);
  // gates read index: g*128 + q*32 + nt*16 + b15 (verified vs xsrc mapping)
  int xrd = q * 32 + nt * 16 + b15;
  // producer h-store offset (R12-verified)
  int hoff = (((blk >> 2) * 2 + nt) * 64 + (blk & 3) * 16 + b15) * 8 + mt * 4 + q;
  // flag id: nt-major so same-nt producers are contiguous
  int fid = nt * 256 + blk * 2 + mt;
  const u32* pollbase = sync + (size_t)nt * 256 * 4;
  float c_reg = 0.f;
  __syncthreads();                   // Ws + XPs[..][0] staged (drains vmcnt)

  u32x4 qA[8], qB[8], qC[8];
#define ISSUE8(BUF, T0)                                                     \
  _Pragma("unroll")                                                         \
  for (int t = 0; t < 8; ++t) {                                             \
    asm volatile("global_load_dwordx4 %0, %1, off sc0 sc1"                  \
                 : "=v"(BUF[t])                                             \
                 : "v"(hs + (((T0) + t) * 2 + nt) * 512 + l * 8));          \
  }
#define MFMA8(BUF, KT0)                                                     \
  _Pragma("unroll")                                                         \
  for (int t = 0; t < 8; ++t) {                                             \
    int kt = (KT0) + t;                                                     \
    short8 wfr = *(const short8*)(Ws + (kt * 2 + mt) * 512 + l * 8);        \
    short8 bfr = __builtin_bit_cast(short8, BUF[t]);                        \
    if (t & 1)                                                              \
      a1 = __builtin_amdgcn_mfma_f32_16x16x32_bf16(wfr, bfr, a1, 0, 0, 0);  \
    else                                                                    \
      a0 = __builtin_amdgcn_mfma_f32_16x16x32_bf16(wfr, bfr, a0, 0, 0, 0);  \
  }

  for (int s = 0; s < SEQ; ++s) {
    // ---- poll the 256 same-nt producer flags >= s (4 loads/lane) ---------
    {
      u32 tgt = (u32)s;
      int guard = 0;
      for (;;) {
        u32 f0 = __hip_atomic_load(pollbase + (l) * 4, __ATOMIC_RELAXED,
                                   __HIP_MEMORY_SCOPE_AGENT);
        u32 f1 = __hip_atomic_load(pollbase + (64 + l) * 4, __ATOMIC_RELAXED,
                                   __HIP_MEMORY_SCOPE_AGENT);
        u32 f2 = __hip_atomic_load(pollbase + (128 + l) * 4, __ATOMIC_RELAXED,
                                   __HIP_MEMORY_SCOPE_AGENT);
        u32 f3 = __hip_atomic_load(pollbase + (192 + l) * 4, __ATOMIC_RELAXED,
                                   __HIP_MEMORY_SCOPE_AGENT);
        if (f0 >= tgt && f1 >= tgt && f2 >= tgt && f3 >= tgt) break;
        __builtin_amdgcn_s_sleep(1);
        if (++guard > 1000000) break;    // fail-fast anti-hang bailout
      }
    }
    asm volatile("" ::: "memory");
    __builtin_amdgcn_sched_barrier(0);

    const u16* hs = (s == 0) ? h0 : (hX + (size_t)(s - 1) * 32768);
    // ---- xp prefetch for s+1 (oldest vmem op; free drain at vmcnt(16)) ---
    {
      int sp = (s + 1 < SEQ) ? s + 1 : s;
      gload_lds16(xp2 + ((size_t)sp * 128 + blk) * 1024 + xsrc,
                  &XPs[w][(s + 1) & 1][l * 8]);
    }
    // ---- issue chunks 0..2 (24 tile loads straight to regs) --------------
    ISSUE8(qA, 0) ISSUE8(qB, 8) ISSUE8(qC, 16)

    f32x4 a0 = {0.f, 0.f, 0.f, 0.f}, a1 = {0.f, 0.f, 0.f, 0.f};
    asm volatile("s_waitcnt vmcnt(16)" ::: "memory");   // qA ready (+xp done)
    __builtin_amdgcn_sched_barrier(0);
    MFMA8(qA, 0)
    ISSUE8(qA, 24)                                      // chunk 3 into qA
    asm volatile("s_waitcnt vmcnt(16)" ::: "memory");   // qB ready
    __builtin_amdgcn_sched_barrier(0);
    MFMA8(qB, 8)
    asm volatile("s_waitcnt vmcnt(8)" ::: "memory");    // qC ready
    __builtin_amdgcn_sched_barrier(0);
    MFMA8(qC, 16)
    asm volatile("s_waitcnt vmcnt(0)" ::: "memory");    // chunk 3 ready
    __builtin_amdgcn_sched_barrier(0);
    MFMA8(qA, 24)
    f32x4 z4 = a0 + a1;

    // ---- gates fully in registers (xp from own LDS slice) ----------------
    const u16* xp = XPs[w][s & 1];
    float zi = z4[0] + bf2f(xp[xrd]);
    float zf = z4[1] + bf2f(xp[128 + xrd]);
    float zo = z4[2] + bf2f(xp[256 + xrd]);
    float zg = z4[3] + bf2f(xp[384 + xrd]);
    float ig = 1.f / (1.f + __expf(-zi));
    float fg = 1.f / (1.f + __expf(-zf));
    float og = 1.f / (1.f + __expf(-zo));
    float gg = tanh_fast(zg);
    c_reg = 1.f / (1.f + __expf(-(fg * c_reg + ig * gg)));  // nonstandard cell
    float h = tanh_fast(c_reg) * og;

    // ---- h-store -> own ack -> own flag (no block coupling) --------------
    __hip_atomic_store(hX + (size_t)s * 32768 + hoff, f2bf(h),
                       __ATOMIC_RELAXED, __HIP_MEMORY_SCOPE_AGENT);
    asm volatile("s_waitcnt vmcnt(0)" ::: "memory");    // this wave's h acked
    __builtin_amdgcn_sched_barrier(0);
    if (l == 0)
      __hip_atomic_store(sync + fid * 4, (u32)(s + 1), __ATOMIC_RELAXED,
                         __HIP_MEMORY_SCOPE_AGENT);
  }
#undef ISSUE8
#undef MFMA8
}

// ---------------- phase 3: relayout h history -> out (f32) ----------------
__global__ void k_out(const u16* __restrict__ hx, float* __restrict__ out) {
  int t = blockIdx.x * 256 + threadIdx.x;
  int d0 = (t & 127) << 3;
  int rem = t >> 7;
  int s = rem & 511, b = rem >> 9;
  int kt = d0 >> 5, jg = (d0 & 31) >> 3, ct = b >> 4;
  const u16* src = hx + (size_t)s * 32768 +
                   (size_t)(((kt * 2 + ct) * 64 + jg * 16 + (b & 15)) * 8);
  ushort4 v0 = *(const ushort4*)src;
  ushort4 v1 = *(const ushort4*)(src + 4);
  float4 o0 = { bf2f(v0.x), bf2f(v0.y), bf2f(v0.z), bf2f(v0.w) };
  float4 o1 = { bf2f(v1.x), bf2f(v1.y), bf2f(v1.z), bf2f(v1.w) };
  float* dst = out + (size_t)(b * SEQ + s) * DIM + d0;
  *(float4*)dst = o0;
  *(float4*)(dst + 4) = o1;
}

// ---------------------------------------------------------------------------
extern "C" void kernel_launch(void* const* d_in, const int* in_sizes, int n_in,
                              void* d_out, int out_size, void* d_ws,
                              size_t ws_size, hipStream_t stream) {
  const float* X   = (const float*)d_in[0];
  const float* Ui  = (const float*)d_in[1];
  const float* Wi  = (const float*)d_in[2];
  const float* Uf  = (const float*)d_in[3];
  const float* Wf  = (const float*)d_in[4];
  const float* Uo  = (const float*)d_in[5];
  const float* Wo  = (const float*)d_in[6];
  const float* Ug  = (const float*)d_in[7];
  const float* Wg  = (const float*)d_in[8];
  const float* bi  = (const float*)d_in[9];
  const float* bfv = (const float*)d_in[10];
  const float* bo  = (const float*)d_in[11];
  const float* bg  = (const float*)d_in[12];
  char* ws = (char*)d_ws;
  u16* Xt      = (u16*)(ws + OFF_XT);      // Xt for gemm; then h slots 0..511
  u16* Ubt     = (u16*)(ws + OFF_UBT);     // U^T for gemm; then h slot -1 (zeros)
  u16* Wg2     = (u16*)(ws + OFF_WG2);
  u16* xp2     = (u16*)(ws + OFF_XPROJ);
  float* biasc = (float*)(ws + OFF_BIAS);
  u32* sync    = (u32*)(ws + OFF_SYNC);
  float* out   = (float*)d_out;

  k_init<<<24, 256, 0, stream>>>(biasc, sync, bi, bfv, bo, bg);
  k_prep_w<<<2048, 256, 0, stream>>>(Ui, Wi, Uf, Wf, Uo, Wo, Ug, Wg, Ubt, Wg2);
  k_prep_x<<<16384, 256, 0, stream>>>(X, Xt);
  k_gemm<<<dim3(32, 128), 256, 0, stream>>>(Xt, Ubt, biasc, xp2);
  k_zero<<<16, 256, 0, stream>>>((u32x4*)Ubt);   // after gemm: Ubt dead -> zeros
  k_rec<<<NB, 256, 0, stream>>>(Wg2, xp2, Xt, Ubt, sync);
  k_out<<<8192, 256, 0, stream>>>(Xt, out);
}